// Round 7
// baseline (487.691 us; speedup 1.0000x reference)
//
#include <hip/hip_runtime.h>

// GCN link classifier, fp32, CSR-gather aggregation, fused layers.
// R7: k_edge-shaped gathers (float4/lane, 4 neighbor-slots x 8 quads, shfl reduce),
//     x4-unrolled atomic passes (k_deg, k_fill).
// Pipeline (9 dispatches):
//   memset deg; k_deg; k_scan1(+dinv+prescale); k_scan2; k_scan3; k_fill  (CSR)
//   k_l1 : agg1=di*(xs_i+Sum xs_s), h1=relu(agg1@W1+b1), xl2s=di*(h1@W2)
//   k_l2 : agg2=di*(xl2s_i+Sum xl2s_s), h2=relu(agg2+b2), gt/gb=h2@Wm1
//   k_edge: out[e] = relu(gt[u]+gb[v]+bm1)@Wm2 + bm2    (8 lanes/edge)

#define HIDN 32
#define SCAN_B 256

__global__ void k_deg(const int* __restrict__ dst, int E, int* __restrict__ deg) {
    int t = blockIdx.x * blockDim.x + threadIdx.x;
    int e = t * 4;
    if (e + 3 < E) {
        int4 d = *reinterpret_cast<const int4*>(dst + e);
        atomicAdd(&deg[d.x], 1);
        atomicAdd(&deg[d.y], 1);
        atomicAdd(&deg[d.z], 1);
        atomicAdd(&deg[d.w], 1);
    } else {
        for (; e < E; ++e) atomicAdd(&deg[dst[e]], 1);
    }
}

// per-block exclusive scan; bsum[b] = block total; dinv = rsqrt(deg+1);
// also prescale xs = dinv * x for this block's 256 nodes.
__global__ void k_scan1(const int* __restrict__ deg, int N,
                        int* __restrict__ part, int* __restrict__ bsum,
                        float* __restrict__ dinv,
                        const float4* __restrict__ x4, float4* __restrict__ xs4) {
    __shared__ int sh[SCAN_B];
    __shared__ float dsh[SCAN_B];
    int t = threadIdx.x, i = blockIdx.x * SCAN_B + t;
    int v = (i < N) ? deg[i] : 0;
    float dv = rsqrtf((float)(v + 1));       // +1 = self loop
    if (i < N) dinv[i] = dv;
    dsh[t] = dv;
    sh[t] = v; __syncthreads();
    for (int o = 1; o < SCAN_B; o <<= 1) {
        int a = (t >= o) ? sh[t - o] : 0;
        __syncthreads();
        sh[t] += a;
        __syncthreads();
    }
    if (i < N) part[i] = sh[t] - v;          // exclusive
    if (t == SCAN_B - 1) bsum[blockIdx.x] = sh[t];
#pragma unroll
    for (int it = 0; it < 8; ++it) {
        int q = it * SCAN_B + t;             // quad within block
        int g = blockIdx.x * (SCAN_B * 8) + q;
        if (g < N * 8) {
            float w = dsh[q >> 3];
            float4 a = x4[g];
            a.x *= w; a.y *= w; a.z *= w; a.w *= w;
            xs4[g] = a;
        }
    }
}

// single-block exclusive scan of block sums (nb <= 1024)
__global__ void k_scan2(int* __restrict__ bsum, int nb) {
    __shared__ int sh[1024];
    int t = threadIdx.x;
    int v = (t < nb) ? bsum[t] : 0;
    sh[t] = v; __syncthreads();
    for (int o = 1; o < 1024; o <<= 1) {
        int a = (t >= o) ? sh[t - o] : 0;
        __syncthreads();
        sh[t] += a;
        __syncthreads();
    }
    if (t < nb) bsum[t] = sh[t] - v;         // exclusive, in place
}

// rowptr[i] = part[i] + bsum[i/SCAN_B]; cursor = rowptr; rowptr[N] = E
__global__ void k_scan3(const int* __restrict__ part, const int* __restrict__ bsum,
                        int N, int E, int* __restrict__ rowptr, int* __restrict__ cursor) {
    int i = blockIdx.x * blockDim.x + threadIdx.x;
    if (i < N) {
        int r = part[i] + bsum[i / SCAN_B];
        rowptr[i] = r;
        cursor[i] = r;
    }
    if (i == N) rowptr[N] = E;
}

__global__ void k_fill(const int* __restrict__ src, const int* __restrict__ dst, int E,
                       int* __restrict__ cursor, int* __restrict__ csr) {
    int t = blockIdx.x * blockDim.x + threadIdx.x;
    int e = t * 4;
    if (e + 3 < E) {
        int4 s = *reinterpret_cast<const int4*>(src + e);
        int4 d = *reinterpret_cast<const int4*>(dst + e);
        int j0 = atomicAdd(&cursor[d.x], 1);
        int j1 = atomicAdd(&cursor[d.y], 1);
        int j2 = atomicAdd(&cursor[d.z], 1);
        int j3 = atomicAdd(&cursor[d.w], 1);
        csr[j0] = s.x; csr[j1] = s.y; csr[j2] = s.z; csr[j3] = s.w;
    } else {
        for (; e < E; ++e) {
            int j = atomicAdd(&cursor[dst[e]], 1);
            csr[j] = src[e];
        }
    }
}

// ---- fused layer 1 ----
// Gather stage: per node, 32 lanes = 4 neighbor-slots (q) x 8 feature-quads (c);
// each lane accumulates float4; shfl_xor(8,16) reduces across slots.
// GEMM stage: h1 = relu(agg1@W1+b1); xl2s = di*(h1@W2).
__global__ __launch_bounds__(256) void k_l1(
        const float4* __restrict__ xs4, const float* __restrict__ dinv,
        const int* __restrict__ rowptr, const int* __restrict__ csr,
        const float* __restrict__ W1, const float* __restrict__ b1,
        const float* __restrict__ W2, int N, float* __restrict__ xl2s) {
    __shared__ float4 ash4[8][9];            // agg row per node (36-float stride)
    __shared__ float hsh[8][129];
    int lane = threadIdx.x & 31, ln = threadIdx.x >> 5;
    int i = blockIdx.x * 8 + ln;
    int c = lane & 7;                        // feature quad
    int q = lane >> 3;                       // neighbor slot
    float di = 0.f;
    float4 acc = make_float4(0.f, 0.f, 0.f, 0.f);
    int beg = 0, end = 0;
    if (i < N) {
        di = dinv[i];
        beg = rowptr[i]; end = rowptr[i + 1];
        if (q == 0) acc = xs4[(size_t)i * 8 + c];   // self-loop (pre-scaled)
    }
    int nb = (end - beg + 3) >> 2;           // batches of 4 neighbors
    int p = beg + q;
    int b = 0;
    for (; b + 2 <= nb; b += 2) {
        int i0 = p + (b << 2), i1 = i0 + 4;
        int s0 = csr[i0 < end ? i0 : (end - 1)];
        int s1 = csr[i1 < end ? i1 : (end - 1)];
        float4 a0 = xs4[(size_t)s0 * 8 + c];
        float4 a1 = xs4[(size_t)s1 * 8 + c];
        if (i0 < end) { acc.x += a0.x; acc.y += a0.y; acc.z += a0.z; acc.w += a0.w; }
        if (i1 < end) { acc.x += a1.x; acc.y += a1.y; acc.z += a1.z; acc.w += a1.w; }
    }
    if (b < nb) {
        int i0 = p + (b << 2);
        int s0 = csr[i0 < end ? i0 : (end - 1)];
        float4 a0 = xs4[(size_t)s0 * 8 + c];
        if (i0 < end) { acc.x += a0.x; acc.y += a0.y; acc.z += a0.z; acc.w += a0.w; }
    }
    // reduce across the 4 neighbor slots (lanes differ by 8, 16 within node group)
    acc.x += __shfl_xor(acc.x, 8);  acc.y += __shfl_xor(acc.y, 8);
    acc.z += __shfl_xor(acc.z, 8);  acc.w += __shfl_xor(acc.w, 8);
    acc.x += __shfl_xor(acc.x, 16); acc.y += __shfl_xor(acc.y, 16);
    acc.z += __shfl_xor(acc.z, 16); acc.w += __shfl_xor(acc.w, 16);
    if (q == 0) {
        acc.x *= di; acc.y *= di; acc.z *= di; acc.w *= di;
        ash4[ln][c] = acc;
    }
    __syncthreads();
    int j = lane;
    if (i < N) {
        const float* arow = (const float*)&ash4[ln][0];
        float h0 = b1[j], h1v = b1[j + 32], h2v = b1[j + 64], h3v = b1[j + 96];
#pragma unroll
        for (int k = 0; k < 32; ++k) {
            float a = arow[k];
            h0  = fmaf(a, W1[k * 128 + j     ], h0);
            h1v = fmaf(a, W1[k * 128 + j + 32], h1v);
            h2v = fmaf(a, W1[k * 128 + j + 64], h2v);
            h3v = fmaf(a, W1[k * 128 + j + 96], h3v);
        }
        hsh[ln][j]      = fmaxf(h0, 0.f);
        hsh[ln][j + 32] = fmaxf(h1v, 0.f);
        hsh[ln][j + 64] = fmaxf(h2v, 0.f);
        hsh[ln][j + 96] = fmaxf(h3v, 0.f);
    }
    __syncthreads();
    if (i >= N) return;
    float s2 = 0.f;
#pragma unroll 16
    for (int k = 0; k < 128; ++k) s2 = fmaf(hsh[ln][k], W2[k * 32 + j], s2);
    xl2s[(size_t)i * 32 + j] = di * s2;        // pre-scaled for layer 2
}

// ---- fused layer 2 + edge-MLP factorization ----
__global__ __launch_bounds__(256) void k_l2(
        const float4* __restrict__ xl2s4, const float* __restrict__ dinv,
        const int* __restrict__ rowptr, const int* __restrict__ csr,
        const float* __restrict__ b2, const float* __restrict__ Wm1,
        int N, float* __restrict__ gt, float* __restrict__ gb) {
    __shared__ float4 hsh4[8][9];
    int lane = threadIdx.x & 31, ln = threadIdx.x >> 5;
    int i = blockIdx.x * 8 + ln;
    int c = lane & 7;
    int q = lane >> 3;
    float di = 0.f;
    float4 acc = make_float4(0.f, 0.f, 0.f, 0.f);
    int beg = 0, end = 0;
    if (i < N) {
        di = dinv[i];
        beg = rowptr[i]; end = rowptr[i + 1];
        if (q == 0) acc = xl2s4[(size_t)i * 8 + c];
    }
    int nb = (end - beg + 3) >> 2;
    int p = beg + q;
    int b = 0;
    for (; b + 2 <= nb; b += 2) {
        int i0 = p + (b << 2), i1 = i0 + 4;
        int s0 = csr[i0 < end ? i0 : (end - 1)];
        int s1 = csr[i1 < end ? i1 : (end - 1)];
        float4 a0 = xl2s4[(size_t)s0 * 8 + c];
        float4 a1 = xl2s4[(size_t)s1 * 8 + c];
        if (i0 < end) { acc.x += a0.x; acc.y += a0.y; acc.z += a0.z; acc.w += a0.w; }
        if (i1 < end) { acc.x += a1.x; acc.y += a1.y; acc.z += a1.z; acc.w += a1.w; }
    }
    if (b < nb) {
        int i0 = p + (b << 2);
        int s0 = csr[i0 < end ? i0 : (end - 1)];
        float4 a0 = xl2s4[(size_t)s0 * 8 + c];
        if (i0 < end) { acc.x += a0.x; acc.y += a0.y; acc.z += a0.z; acc.w += a0.w; }
    }
    acc.x += __shfl_xor(acc.x, 8);  acc.y += __shfl_xor(acc.y, 8);
    acc.z += __shfl_xor(acc.z, 8);  acc.w += __shfl_xor(acc.w, 8);
    acc.x += __shfl_xor(acc.x, 16); acc.y += __shfl_xor(acc.y, 16);
    acc.z += __shfl_xor(acc.z, 16); acc.w += __shfl_xor(acc.w, 16);
    if (q == 0) {
        const float4* b2q = reinterpret_cast<const float4*>(b2);
        float4 bb = b2q[c];
        float4 h2;
        h2.x = fmaxf(fmaf(acc.x, di, bb.x), 0.f);
        h2.y = fmaxf(fmaf(acc.y, di, bb.y), 0.f);
        h2.z = fmaxf(fmaf(acc.z, di, bb.z), 0.f);
        h2.w = fmaxf(fmaf(acc.w, di, bb.w), 0.f);
        hsh4[ln][c] = h2;
    }
    __syncthreads();
    if (i >= N) return;
    int j = lane;
    const float* hrow = (const float*)&hsh4[ln][0];
    float st = 0.f, sb = 0.f;
#pragma unroll
    for (int k = 0; k < 32; ++k) {
        float a = hrow[k];
        st = fmaf(a, Wm1[k * 32 + j], st);
        sb = fmaf(a, Wm1[(k + 32) * 32 + j], sb);
    }
    gt[(size_t)i * 32 + j] = st;
    gb[(size_t)i * 32 + j] = sb;
}

// out[e] = relu(gt[u] + gb[v] + bm1) @ Wm2 + bm2   (8 lanes/edge)
__global__ void k_edge(const int* __restrict__ ps, const int* __restrict__ pd, int Ep,
                       const int* __restrict__ ns, const int* __restrict__ nd, int En,
                       const float4* __restrict__ gt4, const float4* __restrict__ gb4,
                       const float* __restrict__ bm1, const float* __restrict__ Wm2,
                       const float* __restrict__ bm2, float2* __restrict__ out) {
    int t = blockIdx.x * blockDim.x + threadIdx.x;   // E*8 threads
    int e = t >> 3, q = t & 7;
    int E = Ep + En;
    if (e >= E) return;
    int u, v;
    if (e < Ep) { u = ps[e]; v = pd[e]; }
    else        { u = ns[e - Ep]; v = nd[e - Ep]; }
    float4 a = gt4[(size_t)u * 8 + q];
    float4 b = gb4[(size_t)v * 8 + q];
    int k0 = q * 4;
    float o0 = 0.f, o1 = 0.f, h;
    h = fmaxf(a.x + b.x + bm1[k0 + 0], 0.f);
    o0 = fmaf(h, Wm2[(k0 + 0) * 2 + 0], o0); o1 = fmaf(h, Wm2[(k0 + 0) * 2 + 1], o1);
    h = fmaxf(a.y + b.y + bm1[k0 + 1], 0.f);
    o0 = fmaf(h, Wm2[(k0 + 1) * 2 + 0], o0); o1 = fmaf(h, Wm2[(k0 + 1) * 2 + 1], o1);
    h = fmaxf(a.z + b.z + bm1[k0 + 2], 0.f);
    o0 = fmaf(h, Wm2[(k0 + 2) * 2 + 0], o0); o1 = fmaf(h, Wm2[(k0 + 2) * 2 + 1], o1);
    h = fmaxf(a.w + b.w + bm1[k0 + 3], 0.f);
    o0 = fmaf(h, Wm2[(k0 + 3) * 2 + 0], o0); o1 = fmaf(h, Wm2[(k0 + 3) * 2 + 1], o1);
    o0 += __shfl_down(o0, 4, 8); o1 += __shfl_down(o1, 4, 8);
    o0 += __shfl_down(o0, 2, 8); o1 += __shfl_down(o1, 2, 8);
    o0 += __shfl_down(o0, 1, 8); o1 += __shfl_down(o1, 1, 8);
    if (q == 0) out[e] = make_float2(o0 + bm2[0], o1 + bm2[1]);
}

extern "C" void kernel_launch(void* const* d_in, const int* in_sizes, int n_in,
                              void* d_out, int out_size, void* d_ws, size_t ws_size,
                              hipStream_t stream) {
    const float* x   = (const float*)d_in[0];
    const int*   pei = (const int*)d_in[1];
    const int*   nei = (const int*)d_in[2];
    const float* W1  = (const float*)d_in[3];
    const float* b1  = (const float*)d_in[4];
    const float* W2  = (const float*)d_in[5];
    const float* b2  = (const float*)d_in[6];
    const float* Wm1 = (const float*)d_in[7];
    const float* bm1 = (const float*)d_in[8];
    const float* Wm2 = (const float*)d_in[9];
    const float* bm2 = (const float*)d_in[10];

    const int N  = in_sizes[0] / HIDN;
    const int Ep = in_sizes[1] / 2;
    const int En = in_sizes[2] / 2;
    const int* ps = pei;            // pos src
    const int* pd = pei + Ep;       // pos dst
    const int* ns = nei;
    const int* nd = nei + En;
    const int nb = (N + SCAN_B - 1) / SCAN_B;   // scan blocks (<= 1024)

    // workspace layout (256B-aligned slabs)
    char* ws = (char*)d_ws;
    size_t off = 0;
    auto alloc = [&](size_t bytes) { size_t o = off; off += (bytes + 255) & ~(size_t)255; return o; };
    int*   deg    = (int*)(ws + alloc((size_t)N * 4));
    float* dinv   = (float*)(ws + alloc((size_t)N * 4));
    int*   part   = (int*)(ws + alloc((size_t)N * 4));
    int*   bsum   = (int*)(ws + alloc((size_t)1024 * 4));
    int*   rowptr = (int*)(ws + alloc((size_t)(N + 1) * 4));
    int*   cursor = (int*)(ws + alloc((size_t)N * 4));
    int*   csr    = (int*)(ws + alloc((size_t)Ep * 4));
    float* xs     = (float*)(ws + alloc((size_t)N * HIDN * 4));
    float* xl2s   = (float*)(ws + alloc((size_t)N * HIDN * 4));
    float* gt     = (float*)(ws + alloc((size_t)N * HIDN * 4));
    float* gb     = (float*)(ws + alloc((size_t)N * HIDN * 4));

    // ---- CSR build (once; reused by both layers) + prescale ----
    hipMemsetAsync(deg, 0, (size_t)N * 4, stream);
    {
        int th = (Ep + 3) / 4;
        k_deg<<<(th + 255) / 256, 256, 0, stream>>>(pd, Ep, deg);
    }
    k_scan1<<<nb, SCAN_B, 0, stream>>>(deg, N, part, bsum, dinv,
                                       (const float4*)x, (float4*)xs);
    k_scan2<<<1, 1024, 0, stream>>>(bsum, nb);
    k_scan3<<<(N + 256) / 256, 256, 0, stream>>>(part, bsum, N, Ep, rowptr, cursor);
    {
        int th = (Ep + 3) / 4;
        k_fill<<<(th + 255) / 256, 256, 0, stream>>>(ps, pd, Ep, cursor, csr);
    }

    // ---- fused GCN layers ----
    k_l1<<<(N + 7) / 8, 256, 0, stream>>>((const float4*)xs, dinv, rowptr, csr,
                                          W1, b1, W2, N, xl2s);
    k_l2<<<(N + 7) / 8, 256, 0, stream>>>((const float4*)xl2s, dinv, rowptr, csr,
                                          b2, Wm1, N, gt, gb);

    // ---- edge MLP over pos+neg edges (8 lanes/edge) ----
    {
        size_t threads = (size_t)(Ep + En) * 8;
        k_edge<<<(int)((threads + 255) / 256), 256, 0, stream>>>(
            ps, pd, Ep, ns, nd, En,
            (const float4*)gt, (const float4*)gb,
            bm1, Wm2, bm2, (float2*)d_out);
    }
}

// Round 8
// 463.984 us; speedup vs baseline: 1.0511x; 1.0511x over previous
//
#include <hip/hip_runtime.h>

// GCN link classifier, fp32, CSR-gather aggregation.
// R8: sweep-partitioned CSR fill (kills 16x write amplification),
//     de-fused gather/MLP kernels (observability + occupancy),
//     simple k_deg.
// Pipeline (14 dispatches):
//   memset deg; k_deg; k_scan1(+dinv+prescale); k_scan2; k_scan3; k_fill x4
//   k_gather(xs)->agg1; k_mlp1(agg1)->xl2s; k_gather(xl2s)->agg2;
//   k_mlp2(agg2)->gt,gb; k_edge -> out

#define HIDN 32
#define SCAN_B 256

__global__ void k_deg(const int* __restrict__ dst, int E, int* __restrict__ deg) {
    int e = blockIdx.x * blockDim.x + threadIdx.x;
    if (e < E) atomicAdd(&deg[dst[e]], 1);
}

// per-block exclusive scan; bsum[b] = block total; dinv = rsqrt(deg+1);
// also prescale xs = dinv * x for this block's 256 nodes.
__global__ void k_scan1(const int* __restrict__ deg, int N,
                        int* __restrict__ part, int* __restrict__ bsum,
                        float* __restrict__ dinv,
                        const float4* __restrict__ x4, float4* __restrict__ xs4) {
    __shared__ int sh[SCAN_B];
    __shared__ float dsh[SCAN_B];
    int t = threadIdx.x, i = blockIdx.x * SCAN_B + t;
    int v = (i < N) ? deg[i] : 0;
    float dv = rsqrtf((float)(v + 1));       // +1 = self loop
    if (i < N) dinv[i] = dv;
    dsh[t] = dv;
    sh[t] = v; __syncthreads();
    for (int o = 1; o < SCAN_B; o <<= 1) {
        int a = (t >= o) ? sh[t - o] : 0;
        __syncthreads();
        sh[t] += a;
        __syncthreads();
    }
    if (i < N) part[i] = sh[t] - v;          // exclusive
    if (t == SCAN_B - 1) bsum[blockIdx.x] = sh[t];
#pragma unroll
    for (int it = 0; it < 8; ++it) {
        int q = it * SCAN_B + t;             // quad within block
        int g = blockIdx.x * (SCAN_B * 8) + q;
        if (g < N * 8) {
            float w = dsh[q >> 3];
            float4 a = x4[g];
            a.x *= w; a.y *= w; a.z *= w; a.w *= w;
            xs4[g] = a;
        }
    }
}

// single-block exclusive scan of block sums (nb <= 1024)
__global__ void k_scan2(int* __restrict__ bsum, int nb) {
    __shared__ int sh[1024];
    int t = threadIdx.x;
    int v = (t < nb) ? bsum[t] : 0;
    sh[t] = v; __syncthreads();
    for (int o = 1; o < 1024; o <<= 1) {
        int a = (t >= o) ? sh[t - o] : 0;
        __syncthreads();
        sh[t] += a;
        __syncthreads();
    }
    if (t < nb) bsum[t] = sh[t] - v;         // exclusive, in place
}

// rowptr[i] = part[i] + bsum[i/SCAN_B]; cursor = rowptr; rowptr[N] = E
__global__ void k_scan3(const int* __restrict__ part, const int* __restrict__ bsum,
                        int N, int E, int* __restrict__ rowptr, int* __restrict__ cursor) {
    int i = blockIdx.x * blockDim.x + threadIdx.x;
    if (i < N) {
        int r = part[i] + bsum[i / SCAN_B];
        rowptr[i] = r;
        cursor[i] = r;
    }
    if (i == N) rowptr[N] = E;
}

// sweep-partitioned fill: only edges with dst in [lo,hi) are placed.
// Separate launches per sweep => csr writes concentrate in a ~1.6MB
// cache-resident region that is densely filled (full-line writebacks).
__global__ void k_fill_sweep(const int* __restrict__ src, const int* __restrict__ dst,
                             int E, int lo, int hi,
                             int* __restrict__ cursor, int* __restrict__ csr) {
    int e = blockIdx.x * blockDim.x + threadIdx.x;
    if (e >= E) return;
    int d = dst[e];
    if (d >= lo && d < hi) {
        int j = atomicAdd(&cursor[d], 1);
        csr[j] = src[e];
    }
}

// agg[i] = dinv[i] * ( tbl[i] + Sum_{s in inlist(i)} tbl[s] )   (tbl pre-scaled)
// 8 threads/node (one float4 quad each); unroll-4 independent row loads.
__global__ void k_gather(const float4* __restrict__ tbl, const float* __restrict__ dinv,
                         const int* __restrict__ rowptr, const int* __restrict__ csr,
                         int N, float4* __restrict__ out) {
    int t = blockIdx.x * blockDim.x + threadIdx.x;   // N*8
    if (t >= N * 8) return;
    int i = t >> 3, c = t & 7;
    float di = dinv[i];
    float4 acc = tbl[(size_t)i * 8 + c];             // self-loop term
    int p = rowptr[i], end = rowptr[i + 1];
    for (; p + 3 < end; p += 4) {
        int s0 = csr[p], s1 = csr[p + 1], s2 = csr[p + 2], s3 = csr[p + 3];
        float4 a0 = tbl[(size_t)s0 * 8 + c];
        float4 a1 = tbl[(size_t)s1 * 8 + c];
        float4 a2 = tbl[(size_t)s2 * 8 + c];
        float4 a3 = tbl[(size_t)s3 * 8 + c];
        acc.x += (a0.x + a1.x) + (a2.x + a3.x);
        acc.y += (a0.y + a1.y) + (a2.y + a3.y);
        acc.z += (a0.z + a1.z) + (a2.z + a3.z);
        acc.w += (a0.w + a1.w) + (a2.w + a3.w);
    }
    for (; p < end; ++p) {
        float4 a = tbl[(size_t)csr[p] * 8 + c];
        acc.x += a.x; acc.y += a.y; acc.z += a.z; acc.w += a.w;
    }
    acc.x *= di; acc.y *= di; acc.z *= di; acc.w *= di;
    out[t] = acc;
}

// h1 = relu(agg1@W1+b1) (LDS); xl2s = dinv * (h1@W2)
__global__ __launch_bounds__(256) void k_mlp1(
        const float* __restrict__ agg1, const float* __restrict__ dinv,
        const float* __restrict__ W1, const float* __restrict__ b1,
        const float* __restrict__ W2, int N, float* __restrict__ xl2s) {
    __shared__ float ash[8][33];
    __shared__ float hsh[8][129];
    int j = threadIdx.x & 31, ln = threadIdx.x >> 5;
    int i = blockIdx.x * 8 + ln;
    if (i < N) ash[ln][j] = agg1[(size_t)i * 32 + j];
    __syncthreads();
    if (i < N) {
        float h0 = b1[j], h1v = b1[j + 32], h2v = b1[j + 64], h3v = b1[j + 96];
#pragma unroll
        for (int k = 0; k < 32; ++k) {
            float a = ash[ln][k];
            h0  = fmaf(a, W1[k * 128 + j     ], h0);
            h1v = fmaf(a, W1[k * 128 + j + 32], h1v);
            h2v = fmaf(a, W1[k * 128 + j + 64], h2v);
            h3v = fmaf(a, W1[k * 128 + j + 96], h3v);
        }
        hsh[ln][j]      = fmaxf(h0, 0.f);
        hsh[ln][j + 32] = fmaxf(h1v, 0.f);
        hsh[ln][j + 64] = fmaxf(h2v, 0.f);
        hsh[ln][j + 96] = fmaxf(h3v, 0.f);
    }
    __syncthreads();
    if (i >= N) return;
    float s2 = 0.f;
#pragma unroll 16
    for (int k = 0; k < 128; ++k) s2 = fmaf(hsh[ln][k], W2[k * 32 + j], s2);
    xl2s[(size_t)i * 32 + j] = dinv[i] * s2;   // pre-scaled for layer-2 gather
}

// h2 = relu(agg2+b2) (LDS); gt = h2@Wm1[:32]; gb = h2@Wm1[32:]
__global__ __launch_bounds__(256) void k_mlp2(
        const float* __restrict__ agg2, const float* __restrict__ b2,
        const float* __restrict__ Wm1, int N,
        float* __restrict__ gt, float* __restrict__ gb) {
    __shared__ float hsh[8][33];
    int j = threadIdx.x & 31, ln = threadIdx.x >> 5;
    int i = blockIdx.x * 8 + ln;
    if (i < N) hsh[ln][j] = fmaxf(agg2[(size_t)i * 32 + j] + b2[j], 0.f);
    __syncthreads();
    if (i >= N) return;
    float st = 0.f, sb = 0.f;
#pragma unroll
    for (int k = 0; k < 32; ++k) {
        float a = hsh[ln][k];
        st = fmaf(a, Wm1[k * 32 + j], st);
        sb = fmaf(a, Wm1[(k + 32) * 32 + j], sb);
    }
    gt[(size_t)i * 32 + j] = st;
    gb[(size_t)i * 32 + j] = sb;
}

// out[e] = relu(gt[u] + gb[v] + bm1) @ Wm2 + bm2   (8 lanes/edge)
__global__ void k_edge(const int* __restrict__ ps, const int* __restrict__ pd, int Ep,
                       const int* __restrict__ ns, const int* __restrict__ nd, int En,
                       const float4* __restrict__ gt4, const float4* __restrict__ gb4,
                       const float* __restrict__ bm1, const float* __restrict__ Wm2,
                       const float* __restrict__ bm2, float2* __restrict__ out) {
    int t = blockIdx.x * blockDim.x + threadIdx.x;   // E*8 threads
    int e = t >> 3, q = t & 7;
    int E = Ep + En;
    if (e >= E) return;
    int u, v;
    if (e < Ep) { u = ps[e]; v = pd[e]; }
    else        { u = ns[e - Ep]; v = nd[e - Ep]; }
    float4 a = gt4[(size_t)u * 8 + q];
    float4 b = gb4[(size_t)v * 8 + q];
    int k0 = q * 4;
    float o0 = 0.f, o1 = 0.f, h;
    h = fmaxf(a.x + b.x + bm1[k0 + 0], 0.f);
    o0 = fmaf(h, Wm2[(k0 + 0) * 2 + 0], o0); o1 = fmaf(h, Wm2[(k0 + 0) * 2 + 1], o1);
    h = fmaxf(a.y + b.y + bm1[k0 + 1], 0.f);
    o0 = fmaf(h, Wm2[(k0 + 1) * 2 + 0], o0); o1 = fmaf(h, Wm2[(k0 + 1) * 2 + 1], o1);
    h = fmaxf(a.z + b.z + bm1[k0 + 2], 0.f);
    o0 = fmaf(h, Wm2[(k0 + 2) * 2 + 0], o0); o1 = fmaf(h, Wm2[(k0 + 2) * 2 + 1], o1);
    h = fmaxf(a.w + b.w + bm1[k0 + 3], 0.f);
    o0 = fmaf(h, Wm2[(k0 + 3) * 2 + 0], o0); o1 = fmaf(h, Wm2[(k0 + 3) * 2 + 1], o1);
    o0 += __shfl_down(o0, 4, 8); o1 += __shfl_down(o1, 4, 8);
    o0 += __shfl_down(o0, 2, 8); o1 += __shfl_down(o1, 2, 8);
    o0 += __shfl_down(o0, 1, 8); o1 += __shfl_down(o1, 1, 8);
    if (q == 0) out[e] = make_float2(o0 + bm2[0], o1 + bm2[1]);
}

extern "C" void kernel_launch(void* const* d_in, const int* in_sizes, int n_in,
                              void* d_out, int out_size, void* d_ws, size_t ws_size,
                              hipStream_t stream) {
    const float* x   = (const float*)d_in[0];
    const int*   pei = (const int*)d_in[1];
    const int*   nei = (const int*)d_in[2];
    const float* W1  = (const float*)d_in[3];
    const float* b1  = (const float*)d_in[4];
    const float* W2  = (const float*)d_in[5];
    const float* b2  = (const float*)d_in[6];
    const float* Wm1 = (const float*)d_in[7];
    const float* bm1 = (const float*)d_in[8];
    const float* Wm2 = (const float*)d_in[9];
    const float* bm2 = (const float*)d_in[10];

    const int N  = in_sizes[0] / HIDN;
    const int Ep = in_sizes[1] / 2;
    const int En = in_sizes[2] / 2;
    const int* ps = pei;            // pos src
    const int* pd = pei + Ep;       // pos dst
    const int* ns = nei;
    const int* nd = nei + En;
    const int nb = (N + SCAN_B - 1) / SCAN_B;   // scan blocks (<= 1024)

    // workspace layout (256B-aligned slabs)
    char* ws = (char*)d_ws;
    size_t off = 0;
    auto alloc = [&](size_t bytes) { size_t o = off; off += (bytes + 255) & ~(size_t)255; return o; };
    int*   deg    = (int*)(ws + alloc((size_t)N * 4));
    float* dinv   = (float*)(ws + alloc((size_t)N * 4));
    int*   part   = (int*)(ws + alloc((size_t)N * 4));
    int*   bsum   = (int*)(ws + alloc((size_t)1024 * 4));
    int*   rowptr = (int*)(ws + alloc((size_t)(N + 1) * 4));
    int*   cursor = (int*)(ws + alloc((size_t)N * 4));
    int*   csr    = (int*)(ws + alloc((size_t)Ep * 4));
    float* xs     = (float*)(ws + alloc((size_t)N * HIDN * 4));
    float* agg1   = (float*)(ws + alloc((size_t)N * HIDN * 4));
    float* xl2s   = (float*)(ws + alloc((size_t)N * HIDN * 4));
    float* agg2   = (float*)(ws + alloc((size_t)N * HIDN * 4));
    float* gt     = (float*)(ws + alloc((size_t)N * HIDN * 4));
    float* gb     = (float*)(ws + alloc((size_t)N * HIDN * 4));

    // ---- CSR build (once; reused by both layers) + prescale ----
    hipMemsetAsync(deg, 0, (size_t)N * 4, stream);
    k_deg<<<(Ep + 255) / 256, 256, 0, stream>>>(pd, Ep, deg);
    k_scan1<<<nb, SCAN_B, 0, stream>>>(deg, N, part, bsum, dinv,
                                       (const float4*)x, (float4*)xs);
    k_scan2<<<1, 1024, 0, stream>>>(bsum, nb);
    k_scan3<<<(N + 256) / 256, 256, 0, stream>>>(part, bsum, N, Ep, rowptr, cursor);
    // 4 dst-range sweeps: temporal write clustering -> no write amplification
    {
        int grid = (Ep + 255) / 256;
        for (int s = 0; s < 4; ++s) {
            int lo = (int)((size_t)N * s / 4);
            int hi = (int)((size_t)N * (s + 1) / 4);
            k_fill_sweep<<<grid, 256, 0, stream>>>(ps, pd, Ep, lo, hi, cursor, csr);
        }
    }

    // ---- layer 1 ----
    k_gather<<<(N * 8 + 255) / 256, 256, 0, stream>>>(
        (const float4*)xs, dinv, rowptr, csr, N, (float4*)agg1);
    k_mlp1<<<(N + 7) / 8, 256, 0, stream>>>(agg1, dinv, W1, b1, W2, N, xl2s);

    // ---- layer 2 ----
    k_gather<<<(N * 8 + 255) / 256, 256, 0, stream>>>(
        (const float4*)xl2s, dinv, rowptr, csr, N, (float4*)agg2);
    k_mlp2<<<(N + 7) / 8, 256, 0, stream>>>(agg2, b2, Wm1, N, gt, gb);

    // ---- edge MLP over pos+neg edges (8 lanes/edge) ----
    {
        size_t threads = (size_t)(Ep + En) * 8;
        k_edge<<<(int)((threads + 255) / 256), 256, 0, stream>>>(
            ps, pd, Ep, ns, nd, En,
            (const float4*)gt, (const float4*)gb,
            bm1, Wm2, bm2, (float2*)d_out);
    }
}

// Round 9
// 449.157 us; speedup vs baseline: 1.0858x; 1.0330x over previous
//
#include <hip/hip_runtime.h>
#include <hip/hip_fp16.h>

// GCN link classifier, fp32 compute, CSR-gather aggregation.
// R9: fp16 g-tables for the edge MLP (halves k_edge's random-gather bytes;
//     quantization applied only at the final factorized stage).
// Pipeline (14 dispatches):
//   memset deg; k_deg; k_scan1(+dinv+prescale); k_scan2; k_scan3; k_fill x4
//   k_gather(xs)->agg1; k_mlp1(agg1)->xl2s; k_gather(xl2s)->agg2;
//   k_mlp2(agg2)->gt,gb (fp16); k_edge (4 lanes/edge) -> out

#define HIDN 32
#define SCAN_B 256

__global__ void k_deg(const int* __restrict__ dst, int E, int* __restrict__ deg) {
    int e = blockIdx.x * blockDim.x + threadIdx.x;
    if (e < E) atomicAdd(&deg[dst[e]], 1);
}

// per-block exclusive scan; bsum[b] = block total; dinv = rsqrt(deg+1);
// also prescale xs = dinv * x for this block's 256 nodes.
__global__ void k_scan1(const int* __restrict__ deg, int N,
                        int* __restrict__ part, int* __restrict__ bsum,
                        float* __restrict__ dinv,
                        const float4* __restrict__ x4, float4* __restrict__ xs4) {
    __shared__ int sh[SCAN_B];
    __shared__ float dsh[SCAN_B];
    int t = threadIdx.x, i = blockIdx.x * SCAN_B + t;
    int v = (i < N) ? deg[i] : 0;
    float dv = rsqrtf((float)(v + 1));       // +1 = self loop
    if (i < N) dinv[i] = dv;
    dsh[t] = dv;
    sh[t] = v; __syncthreads();
    for (int o = 1; o < SCAN_B; o <<= 1) {
        int a = (t >= o) ? sh[t - o] : 0;
        __syncthreads();
        sh[t] += a;
        __syncthreads();
    }
    if (i < N) part[i] = sh[t] - v;          // exclusive
    if (t == SCAN_B - 1) bsum[blockIdx.x] = sh[t];
#pragma unroll
    for (int it = 0; it < 8; ++it) {
        int q = it * SCAN_B + t;             // quad within block
        int g = blockIdx.x * (SCAN_B * 8) + q;
        if (g < N * 8) {
            float w = dsh[q >> 3];
            float4 a = x4[g];
            a.x *= w; a.y *= w; a.z *= w; a.w *= w;
            xs4[g] = a;
        }
    }
}

// single-block exclusive scan of block sums (nb <= 1024)
__global__ void k_scan2(int* __restrict__ bsum, int nb) {
    __shared__ int sh[1024];
    int t = threadIdx.x;
    int v = (t < nb) ? bsum[t] : 0;
    sh[t] = v; __syncthreads();
    for (int o = 1; o < 1024; o <<= 1) {
        int a = (t >= o) ? sh[t - o] : 0;
        __syncthreads();
        sh[t] += a;
        __syncthreads();
    }
    if (t < nb) bsum[t] = sh[t] - v;         // exclusive, in place
}

// rowptr[i] = part[i] + bsum[i/SCAN_B]; cursor = rowptr; rowptr[N] = E
__global__ void k_scan3(const int* __restrict__ part, const int* __restrict__ bsum,
                        int N, int E, int* __restrict__ rowptr, int* __restrict__ cursor) {
    int i = blockIdx.x * blockDim.x + threadIdx.x;
    if (i < N) {
        int r = part[i] + bsum[i / SCAN_B];
        rowptr[i] = r;
        cursor[i] = r;
    }
    if (i == N) rowptr[N] = E;
}

// sweep-partitioned fill: only edges with dst in [lo,hi) are placed.
__global__ void k_fill_sweep(const int* __restrict__ src, const int* __restrict__ dst,
                             int E, int lo, int hi,
                             int* __restrict__ cursor, int* __restrict__ csr) {
    int e = blockIdx.x * blockDim.x + threadIdx.x;
    if (e >= E) return;
    int d = dst[e];
    if (d >= lo && d < hi) {
        int j = atomicAdd(&cursor[d], 1);
        csr[j] = src[e];
    }
}

// agg[i] = dinv[i] * ( tbl[i] + Sum_{s in inlist(i)} tbl[s] )   (tbl pre-scaled)
// 8 threads/node (one float4 quad each); unroll-4 independent row loads.
__global__ void k_gather(const float4* __restrict__ tbl, const float* __restrict__ dinv,
                         const int* __restrict__ rowptr, const int* __restrict__ csr,
                         int N, float4* __restrict__ out) {
    int t = blockIdx.x * blockDim.x + threadIdx.x;   // N*8
    if (t >= N * 8) return;
    int i = t >> 3, c = t & 7;
    float di = dinv[i];
    float4 acc = tbl[(size_t)i * 8 + c];             // self-loop term
    int p = rowptr[i], end = rowptr[i + 1];
    for (; p + 3 < end; p += 4) {
        int s0 = csr[p], s1 = csr[p + 1], s2 = csr[p + 2], s3 = csr[p + 3];
        float4 a0 = tbl[(size_t)s0 * 8 + c];
        float4 a1 = tbl[(size_t)s1 * 8 + c];
        float4 a2 = tbl[(size_t)s2 * 8 + c];
        float4 a3 = tbl[(size_t)s3 * 8 + c];
        acc.x += (a0.x + a1.x) + (a2.x + a3.x);
        acc.y += (a0.y + a1.y) + (a2.y + a3.y);
        acc.z += (a0.z + a1.z) + (a2.z + a3.z);
        acc.w += (a0.w + a1.w) + (a2.w + a3.w);
    }
    for (; p < end; ++p) {
        float4 a = tbl[(size_t)csr[p] * 8 + c];
        acc.x += a.x; acc.y += a.y; acc.z += a.z; acc.w += a.w;
    }
    acc.x *= di; acc.y *= di; acc.z *= di; acc.w *= di;
    out[t] = acc;
}

// h1 = relu(agg1@W1+b1) (LDS); xl2s = dinv * (h1@W2)
__global__ __launch_bounds__(256) void k_mlp1(
        const float* __restrict__ agg1, const float* __restrict__ dinv,
        const float* __restrict__ W1, const float* __restrict__ b1,
        const float* __restrict__ W2, int N, float* __restrict__ xl2s) {
    __shared__ float ash[8][33];
    __shared__ float hsh[8][129];
    int j = threadIdx.x & 31, ln = threadIdx.x >> 5;
    int i = blockIdx.x * 8 + ln;
    if (i < N) ash[ln][j] = agg1[(size_t)i * 32 + j];
    __syncthreads();
    if (i < N) {
        float h0 = b1[j], h1v = b1[j + 32], h2v = b1[j + 64], h3v = b1[j + 96];
#pragma unroll
        for (int k = 0; k < 32; ++k) {
            float a = ash[ln][k];
            h0  = fmaf(a, W1[k * 128 + j     ], h0);
            h1v = fmaf(a, W1[k * 128 + j + 32], h1v);
            h2v = fmaf(a, W1[k * 128 + j + 64], h2v);
            h3v = fmaf(a, W1[k * 128 + j + 96], h3v);
        }
        hsh[ln][j]      = fmaxf(h0, 0.f);
        hsh[ln][j + 32] = fmaxf(h1v, 0.f);
        hsh[ln][j + 64] = fmaxf(h2v, 0.f);
        hsh[ln][j + 96] = fmaxf(h3v, 0.f);
    }
    __syncthreads();
    if (i >= N) return;
    float s2 = 0.f;
#pragma unroll 16
    for (int k = 0; k < 128; ++k) s2 = fmaf(hsh[ln][k], W2[k * 32 + j], s2);
    xl2s[(size_t)i * 32 + j] = dinv[i] * s2;   // pre-scaled for layer-2 gather
}

// h2 = relu(agg2+b2) (LDS); gt = h2@Wm1[:32]; gb = h2@Wm1[32:]  -> fp16 tables
__global__ __launch_bounds__(256) void k_mlp2(
        const float* __restrict__ agg2, const float* __restrict__ b2,
        const float* __restrict__ Wm1, int N,
        __half* __restrict__ gt, __half* __restrict__ gb) {
    __shared__ float hsh[8][33];
    int j = threadIdx.x & 31, ln = threadIdx.x >> 5;
    int i = blockIdx.x * 8 + ln;
    if (i < N) hsh[ln][j] = fmaxf(agg2[(size_t)i * 32 + j] + b2[j], 0.f);
    __syncthreads();
    if (i >= N) return;
    float st = 0.f, sb = 0.f;
#pragma unroll
    for (int k = 0; k < 32; ++k) {
        float a = hsh[ln][k];
        st = fmaf(a, Wm1[k * 32 + j], st);
        sb = fmaf(a, Wm1[(k + 32) * 32 + j], sb);
    }
    gt[(size_t)i * 32 + j] = __float2half(st);
    gb[(size_t)i * 32 + j] = __float2half(sb);
}

// out[e] = relu(gt[u] + gb[v] + bm1) @ Wm2 + bm2
// 4 lanes/edge: lane q loads 16B (8 halves) of gt[u] and gb[v], computes 8
// hidden units; 4-lane shuffle reduce; lane 0 writes float2.
__global__ void k_edge(const int* __restrict__ ps, const int* __restrict__ pd, int Ep,
                       const int* __restrict__ ns, const int* __restrict__ nd, int En,
                       const float4* __restrict__ gt4, const float4* __restrict__ gb4,
                       const float* __restrict__ bm1, const float* __restrict__ Wm2,
                       const float* __restrict__ bm2, float2* __restrict__ out) {
    int t = blockIdx.x * blockDim.x + threadIdx.x;   // E*4 threads
    int e = t >> 2, q = t & 3;
    int E = Ep + En;
    if (e >= E) return;
    int u, v;
    if (e < Ep) { u = ps[e]; v = pd[e]; }
    else        { u = ns[e - Ep]; v = nd[e - Ep]; }
    float4 araw = gt4[(size_t)u * 4 + q];            // 8 halves of gt row
    float4 braw = gb4[(size_t)v * 4 + q];            // 8 halves of gb row
    const __half* ah = (const __half*)&araw;
    const __half* bh = (const __half*)&braw;
    int k0 = q * 8;
    float o0 = 0.f, o1 = 0.f;
#pragma unroll
    for (int r = 0; r < 8; ++r) {
        float h = fmaxf(__half2float(ah[r]) + __half2float(bh[r]) + bm1[k0 + r], 0.f);
        o0 = fmaf(h, Wm2[(k0 + r) * 2 + 0], o0);
        o1 = fmaf(h, Wm2[(k0 + r) * 2 + 1], o1);
    }
    o0 += __shfl_down(o0, 2, 4); o1 += __shfl_down(o1, 2, 4);
    o0 += __shfl_down(o0, 1, 4); o1 += __shfl_down(o1, 1, 4);
    if (q == 0) out[e] = make_float2(o0 + bm2[0], o1 + bm2[1]);
}

extern "C" void kernel_launch(void* const* d_in, const int* in_sizes, int n_in,
                              void* d_out, int out_size, void* d_ws, size_t ws_size,
                              hipStream_t stream) {
    const float* x   = (const float*)d_in[0];
    const int*   pei = (const int*)d_in[1];
    const int*   nei = (const int*)d_in[2];
    const float* W1  = (const float*)d_in[3];
    const float* b1  = (const float*)d_in[4];
    const float* W2  = (const float*)d_in[5];
    const float* b2  = (const float*)d_in[6];
    const float* Wm1 = (const float*)d_in[7];
    const float* bm1 = (const float*)d_in[8];
    const float* Wm2 = (const float*)d_in[9];
    const float* bm2 = (const float*)d_in[10];

    const int N  = in_sizes[0] / HIDN;
    const int Ep = in_sizes[1] / 2;
    const int En = in_sizes[2] / 2;
    const int* ps = pei;            // pos src
    const int* pd = pei + Ep;       // pos dst
    const int* ns = nei;
    const int* nd = nei + En;
    const int nb = (N + SCAN_B - 1) / SCAN_B;   // scan blocks (<= 1024)

    // workspace layout (256B-aligned slabs)
    char* ws = (char*)d_ws;
    size_t off = 0;
    auto alloc = [&](size_t bytes) { size_t o = off; off += (bytes + 255) & ~(size_t)255; return o; };
    int*    deg    = (int*)(ws + alloc((size_t)N * 4));
    float*  dinv   = (float*)(ws + alloc((size_t)N * 4));
    int*    part   = (int*)(ws + alloc((size_t)N * 4));
    int*    bsum   = (int*)(ws + alloc((size_t)1024 * 4));
    int*    rowptr = (int*)(ws + alloc((size_t)(N + 1) * 4));
    int*    cursor = (int*)(ws + alloc((size_t)N * 4));
    int*    csr    = (int*)(ws + alloc((size_t)Ep * 4));
    float*  xs     = (float*)(ws + alloc((size_t)N * HIDN * 4));
    float*  agg1   = (float*)(ws + alloc((size_t)N * HIDN * 4));
    float*  xl2s   = (float*)(ws + alloc((size_t)N * HIDN * 4));
    float*  agg2   = (float*)(ws + alloc((size_t)N * HIDN * 4));
    __half* gt     = (__half*)(ws + alloc((size_t)N * HIDN * 2));
    __half* gb     = (__half*)(ws + alloc((size_t)N * HIDN * 2));

    // ---- CSR build (once; reused by both layers) + prescale ----
    hipMemsetAsync(deg, 0, (size_t)N * 4, stream);
    k_deg<<<(Ep + 255) / 256, 256, 0, stream>>>(pd, Ep, deg);
    k_scan1<<<nb, SCAN_B, 0, stream>>>(deg, N, part, bsum, dinv,
                                       (const float4*)x, (float4*)xs);
    k_scan2<<<1, 1024, 0, stream>>>(bsum, nb);
    k_scan3<<<(N + 256) / 256, 256, 0, stream>>>(part, bsum, N, Ep, rowptr, cursor);
    // 4 dst-range sweeps: temporal write clustering -> no write amplification
    {
        int grid = (Ep + 255) / 256;
        for (int s = 0; s < 4; ++s) {
            int lo = (int)((size_t)N * s / 4);
            int hi = (int)((size_t)N * (s + 1) / 4);
            k_fill_sweep<<<grid, 256, 0, stream>>>(ps, pd, Ep, lo, hi, cursor, csr);
        }
    }

    // ---- layer 1 ----
    k_gather<<<(N * 8 + 255) / 256, 256, 0, stream>>>(
        (const float4*)xs, dinv, rowptr, csr, N, (float4*)agg1);
    k_mlp1<<<(N + 7) / 8, 256, 0, stream>>>(agg1, dinv, W1, b1, W2, N, xl2s);

    // ---- layer 2 ----
    k_gather<<<(N * 8 + 255) / 256, 256, 0, stream>>>(
        (const float4*)xl2s, dinv, rowptr, csr, N, (float4*)agg2);
    k_mlp2<<<(N + 7) / 8, 256, 0, stream>>>(agg2, b2, Wm1, N, gt, gb);

    // ---- edge MLP over pos+neg edges (4 lanes/edge, fp16 tables) ----
    {
        size_t threads = (size_t)(Ep + En) * 4;
        k_edge<<<(int)((threads + 255) / 256), 256, 0, stream>>>(
            ps, pd, Ep, ns, nd, En,
            (const float4*)gt, (const float4*)gb,
            bm1, Wm2, bm2, (float2*)d_out);
    }
}

// Round 10
// 446.129 us; speedup vs baseline: 1.0932x; 1.0068x over previous
//
#include <hip/hip_runtime.h>
#include <hip/hip_fp16.h>

// GCN link classifier, fp32 compute, CSR-gather aggregation.
// R10: vectorized weight streams in the MLP kernels (float4 loads, 4x fewer
//      VMEM instructions; k-slice x output-quad lane remap + shfl reduce).
// Pipeline (14 dispatches):
//   memset deg; k_deg; k_scan1(+dinv+prescale); k_scan2; k_scan3; k_fill x4
//   k_gather(xs)->agg1; k_mlp1(agg1)->xl2s; k_gather(xl2s)->agg2;
//   k_mlp2(agg2)->gt,gb (fp16); k_edge (4 lanes/edge) -> out

#define HIDN 32
#define SCAN_B 256

struct __align__(8) Half4 { __half2 a, b; };

__global__ void k_deg(const int* __restrict__ dst, int E, int* __restrict__ deg) {
    int e = blockIdx.x * blockDim.x + threadIdx.x;
    if (e < E) atomicAdd(&deg[dst[e]], 1);
}

// per-block exclusive scan; bsum[b] = block total; dinv = rsqrt(deg+1);
// also prescale xs = dinv * x for this block's 256 nodes.
__global__ void k_scan1(const int* __restrict__ deg, int N,
                        int* __restrict__ part, int* __restrict__ bsum,
                        float* __restrict__ dinv,
                        const float4* __restrict__ x4, float4* __restrict__ xs4) {
    __shared__ int sh[SCAN_B];
    __shared__ float dsh[SCAN_B];
    int t = threadIdx.x, i = blockIdx.x * SCAN_B + t;
    int v = (i < N) ? deg[i] : 0;
    float dv = rsqrtf((float)(v + 1));       // +1 = self loop
    if (i < N) dinv[i] = dv;
    dsh[t] = dv;
    sh[t] = v; __syncthreads();
    for (int o = 1; o < SCAN_B; o <<= 1) {
        int a = (t >= o) ? sh[t - o] : 0;
        __syncthreads();
        sh[t] += a;
        __syncthreads();
    }
    if (i < N) part[i] = sh[t] - v;          // exclusive
    if (t == SCAN_B - 1) bsum[blockIdx.x] = sh[t];
#pragma unroll
    for (int it = 0; it < 8; ++it) {
        int q = it * SCAN_B + t;             // quad within block
        int g = blockIdx.x * (SCAN_B * 8) + q;
        if (g < N * 8) {
            float w = dsh[q >> 3];
            float4 a = x4[g];
            a.x *= w; a.y *= w; a.z *= w; a.w *= w;
            xs4[g] = a;
        }
    }
}

// single-block exclusive scan of block sums (nb <= 1024)
__global__ void k_scan2(int* __restrict__ bsum, int nb) {
    __shared__ int sh[1024];
    int t = threadIdx.x;
    int v = (t < nb) ? bsum[t] : 0;
    sh[t] = v; __syncthreads();
    for (int o = 1; o < 1024; o <<= 1) {
        int a = (t >= o) ? sh[t - o] : 0;
        __syncthreads();
        sh[t] += a;
        __syncthreads();
    }
    if (t < nb) bsum[t] = sh[t] - v;         // exclusive, in place
}

// rowptr[i] = part[i] + bsum[i/SCAN_B]; cursor = rowptr; rowptr[N] = E
__global__ void k_scan3(const int* __restrict__ part, const int* __restrict__ bsum,
                        int N, int E, int* __restrict__ rowptr, int* __restrict__ cursor) {
    int i = blockIdx.x * blockDim.x + threadIdx.x;
    if (i < N) {
        int r = part[i] + bsum[i / SCAN_B];
        rowptr[i] = r;
        cursor[i] = r;
    }
    if (i == N) rowptr[N] = E;
}

// sweep-partitioned fill: only edges with dst in [lo,hi) are placed.
__global__ void k_fill_sweep(const int* __restrict__ src, const int* __restrict__ dst,
                             int E, int lo, int hi,
                             int* __restrict__ cursor, int* __restrict__ csr) {
    int e = blockIdx.x * blockDim.x + threadIdx.x;
    if (e >= E) return;
    int d = dst[e];
    if (d >= lo && d < hi) {
        int j = atomicAdd(&cursor[d], 1);
        csr[j] = src[e];
    }
}

// agg[i] = dinv[i] * ( tbl[i] + Sum_{s in inlist(i)} tbl[s] )   (tbl pre-scaled)
// 8 threads/node (one float4 quad each); unroll-4 independent row loads.
__global__ void k_gather(const float4* __restrict__ tbl, const float* __restrict__ dinv,
                         const int* __restrict__ rowptr, const int* __restrict__ csr,
                         int N, float4* __restrict__ out) {
    int t = blockIdx.x * blockDim.x + threadIdx.x;   // N*8
    if (t >= N * 8) return;
    int i = t >> 3, c = t & 7;
    float di = dinv[i];
    float4 acc = tbl[(size_t)i * 8 + c];             // self-loop term
    int p = rowptr[i], end = rowptr[i + 1];
    for (; p + 3 < end; p += 4) {
        int s0 = csr[p], s1 = csr[p + 1], s2 = csr[p + 2], s3 = csr[p + 3];
        float4 a0 = tbl[(size_t)s0 * 8 + c];
        float4 a1 = tbl[(size_t)s1 * 8 + c];
        float4 a2 = tbl[(size_t)s2 * 8 + c];
        float4 a3 = tbl[(size_t)s3 * 8 + c];
        acc.x += (a0.x + a1.x) + (a2.x + a3.x);
        acc.y += (a0.y + a1.y) + (a2.y + a3.y);
        acc.z += (a0.z + a1.z) + (a2.z + a3.z);
        acc.w += (a0.w + a1.w) + (a2.w + a3.w);
    }
    for (; p < end; ++p) {
        float4 a = tbl[(size_t)csr[p] * 8 + c];
        acc.x += a.x; acc.y += a.y; acc.z += a.z; acc.w += a.w;
    }
    acc.x *= di; acc.y *= di; acc.z *= di; acc.w *= di;
    out[t] = acc;
}

// h1 = relu(agg1@W1+b1); xl2s = dinv * (h1@W2)
// Stage 1: lane j -> outputs 4j..4j+3 via float4 W1 row loads.
// Stage 2: lane = ko*8+jo -> float4 of outputs 4jo..4jo+3 over k-slice ko;
//          shfl_xor(8,16) reduces slices.
__global__ __launch_bounds__(256) void k_mlp1(
        const float* __restrict__ agg1, const float* __restrict__ dinv,
        const float* __restrict__ W1, const float* __restrict__ b1,
        const float* __restrict__ W2, int N, float* __restrict__ xl2s) {
    __shared__ float ash[8][33];
    __shared__ float hsh[8][128];
    int j = threadIdx.x & 31, ln = threadIdx.x >> 5;
    int i = blockIdx.x * 8 + ln;
    if (i < N) ash[ln][j] = agg1[(size_t)i * 32 + j];
    __syncthreads();
    if (i < N) {
        float4 hq = *reinterpret_cast<const float4*>(&b1[4 * j]);
#pragma unroll
        for (int k = 0; k < 32; ++k) {
            float a = ash[ln][k];                 // broadcast
            float4 w = *reinterpret_cast<const float4*>(&W1[k * 128 + 4 * j]);
            hq.x = fmaf(a, w.x, hq.x);
            hq.y = fmaf(a, w.y, hq.y);
            hq.z = fmaf(a, w.z, hq.z);
            hq.w = fmaf(a, w.w, hq.w);
        }
        hq.x = fmaxf(hq.x, 0.f); hq.y = fmaxf(hq.y, 0.f);
        hq.z = fmaxf(hq.z, 0.f); hq.w = fmaxf(hq.w, 0.f);
        *reinterpret_cast<float4*>(&hsh[ln][4 * j]) = hq;
    }
    __syncthreads();
    if (i >= N) return;
    int jo = j & 7, ko = j >> 3;
    const float* hrow = &hsh[ln][0];
    float4 s = make_float4(0.f, 0.f, 0.f, 0.f);
#pragma unroll
    for (int kk = 0; kk < 32; ++kk) {
        int k = ko * 32 + kk;
        float a = hrow[k];
        float4 w = *reinterpret_cast<const float4*>(&W2[k * 32 + 4 * jo]);
        s.x = fmaf(a, w.x, s.x);
        s.y = fmaf(a, w.y, s.y);
        s.z = fmaf(a, w.z, s.z);
        s.w = fmaf(a, w.w, s.w);
    }
    s.x += __shfl_xor(s.x, 8);  s.y += __shfl_xor(s.y, 8);
    s.z += __shfl_xor(s.z, 8);  s.w += __shfl_xor(s.w, 8);
    s.x += __shfl_xor(s.x, 16); s.y += __shfl_xor(s.y, 16);
    s.z += __shfl_xor(s.z, 16); s.w += __shfl_xor(s.w, 16);
    if (ko == 0) {
        float d = dinv[i];
        s.x *= d; s.y *= d; s.z *= d; s.w *= d;
        *reinterpret_cast<float4*>(&xl2s[(size_t)i * 32 + 4 * jo]) = s;
    }
}

// h2 = relu(agg2+b2); gt = h2@Wm1[:32]; gb = h2@Wm1[32:]  -> fp16 tables
// Stage 2 lane remap like k_mlp1 (ko slices of 8 k's; float4 Wm1 loads).
__global__ __launch_bounds__(256) void k_mlp2(
        const float* __restrict__ agg2, const float* __restrict__ b2,
        const float* __restrict__ Wm1, int N,
        __half* __restrict__ gt, __half* __restrict__ gb) {
    __shared__ float hsh[8][33];
    int j = threadIdx.x & 31, ln = threadIdx.x >> 5;
    int i = blockIdx.x * 8 + ln;
    if (i < N) hsh[ln][j] = fmaxf(agg2[(size_t)i * 32 + j] + b2[j], 0.f);
    __syncthreads();
    if (i >= N) return;
    int jo = j & 7, ko = j >> 3;
    const float* hrow = &hsh[ln][0];
    float4 st = make_float4(0.f, 0.f, 0.f, 0.f);
    float4 sb = make_float4(0.f, 0.f, 0.f, 0.f);
#pragma unroll
    for (int kk = 0; kk < 8; ++kk) {
        int k = ko * 8 + kk;
        float a = hrow[k];
        float4 wt = *reinterpret_cast<const float4*>(&Wm1[k * 32 + 4 * jo]);
        float4 wb = *reinterpret_cast<const float4*>(&Wm1[(k + 32) * 32 + 4 * jo]);
        st.x = fmaf(a, wt.x, st.x); st.y = fmaf(a, wt.y, st.y);
        st.z = fmaf(a, wt.z, st.z); st.w = fmaf(a, wt.w, st.w);
        sb.x = fmaf(a, wb.x, sb.x); sb.y = fmaf(a, wb.y, sb.y);
        sb.z = fmaf(a, wb.z, sb.z); sb.w = fmaf(a, wb.w, sb.w);
    }
    st.x += __shfl_xor(st.x, 8);  st.y += __shfl_xor(st.y, 8);
    st.z += __shfl_xor(st.z, 8);  st.w += __shfl_xor(st.w, 8);
    st.x += __shfl_xor(st.x, 16); st.y += __shfl_xor(st.y, 16);
    st.z += __shfl_xor(st.z, 16); st.w += __shfl_xor(st.w, 16);
    sb.x += __shfl_xor(sb.x, 8);  sb.y += __shfl_xor(sb.y, 8);
    sb.z += __shfl_xor(sb.z, 8);  sb.w += __shfl_xor(sb.w, 8);
    sb.x += __shfl_xor(sb.x, 16); sb.y += __shfl_xor(sb.y, 16);
    sb.z += __shfl_xor(sb.z, 16); sb.w += __shfl_xor(sb.w, 16);
    if (ko == 0) {
        Half4 ht, hb;
        ht.a = __floats2half2_rn(st.x, st.y);
        ht.b = __floats2half2_rn(st.z, st.w);
        hb.a = __floats2half2_rn(sb.x, sb.y);
        hb.b = __floats2half2_rn(sb.z, sb.w);
        *reinterpret_cast<Half4*>(&gt[(size_t)i * 32 + 4 * jo]) = ht;
        *reinterpret_cast<Half4*>(&gb[(size_t)i * 32 + 4 * jo]) = hb;
    }
}

// out[e] = relu(gt[u] + gb[v] + bm1) @ Wm2 + bm2
// 4 lanes/edge: lane q loads 16B (8 halves) of gt[u] and gb[v], computes 8
// hidden units; 4-lane shuffle reduce; lane 0 writes float2.
__global__ void k_edge(const int* __restrict__ ps, const int* __restrict__ pd, int Ep,
                       const int* __restrict__ ns, const int* __restrict__ nd, int En,
                       const float4* __restrict__ gt4, const float4* __restrict__ gb4,
                       const float* __restrict__ bm1, const float* __restrict__ Wm2,
                       const float* __restrict__ bm2, float2* __restrict__ out) {
    int t = blockIdx.x * blockDim.x + threadIdx.x;   // E*4 threads
    int e = t >> 2, q = t & 3;
    int E = Ep + En;
    if (e >= E) return;
    int u, v;
    if (e < Ep) { u = ps[e]; v = pd[e]; }
    else        { u = ns[e - Ep]; v = nd[e - Ep]; }
    float4 araw = gt4[(size_t)u * 4 + q];            // 8 halves of gt row
    float4 braw = gb4[(size_t)v * 4 + q];            // 8 halves of gb row
    const __half* ah = (const __half*)&araw;
    const __half* bh = (const __half*)&braw;
    int k0 = q * 8;
    float o0 = 0.f, o1 = 0.f;
#pragma unroll
    for (int r = 0; r < 8; ++r) {
        float h = fmaxf(__half2float(ah[r]) + __half2float(bh[r]) + bm1[k0 + r], 0.f);
        o0 = fmaf(h, Wm2[(k0 + r) * 2 + 0], o0);
        o1 = fmaf(h, Wm2[(k0 + r) * 2 + 1], o1);
    }
    o0 += __shfl_down(o0, 2, 4); o1 += __shfl_down(o1, 2, 4);
    o0 += __shfl_down(o0, 1, 4); o1 += __shfl_down(o1, 1, 4);
    if (q == 0) out[e] = make_float2(o0 + bm2[0], o1 + bm2[1]);
}

extern "C" void kernel_launch(void* const* d_in, const int* in_sizes, int n_in,
                              void* d_out, int out_size, void* d_ws, size_t ws_size,
                              hipStream_t stream) {
    const float* x   = (const float*)d_in[0];
    const int*   pei = (const int*)d_in[1];
    const int*   nei = (const int*)d_in[2];
    const float* W1  = (const float*)d_in[3];
    const float* b1  = (const float*)d_in[4];
    const float* W2  = (const float*)d_in[5];
    const float* b2  = (const float*)d_in[6];
    const float* Wm1 = (const float*)d_in[7];
    const float* bm1 = (const float*)d_in[8];
    const float* Wm2 = (const float*)d_in[9];
    const float* bm2 = (const float*)d_in[10];

    const int N  = in_sizes[0] / HIDN;
    const int Ep = in_sizes[1] / 2;
    const int En = in_sizes[2] / 2;
    const int* ps = pei;            // pos src
    const int* pd = pei + Ep;       // pos dst
    const int* ns = nei;
    const int* nd = nei + En;
    const int nb = (N + SCAN_B - 1) / SCAN_B;   // scan blocks (<= 1024)

    // workspace layout (256B-aligned slabs)
    char* ws = (char*)d_ws;
    size_t off = 0;
    auto alloc = [&](size_t bytes) { size_t o = off; off += (bytes + 255) & ~(size_t)255; return o; };
    int*    deg    = (int*)(ws + alloc((size_t)N * 4));
    float*  dinv   = (float*)(ws + alloc((size_t)N * 4));
    int*    part   = (int*)(ws + alloc((size_t)N * 4));
    int*    bsum   = (int*)(ws + alloc((size_t)1024 * 4));
    int*    rowptr = (int*)(ws + alloc((size_t)(N + 1) * 4));
    int*    cursor = (int*)(ws + alloc((size_t)N * 4));
    int*    csr    = (int*)(ws + alloc((size_t)Ep * 4));
    float*  xs     = (float*)(ws + alloc((size_t)N * HIDN * 4));
    float*  agg1   = (float*)(ws + alloc((size_t)N * HIDN * 4));
    float*  xl2s   = (float*)(ws + alloc((size_t)N * HIDN * 4));
    float*  agg2   = (float*)(ws + alloc((size_t)N * HIDN * 4));
    __half* gt     = (__half*)(ws + alloc((size_t)N * HIDN * 2));
    __half* gb     = (__half*)(ws + alloc((size_t)N * HIDN * 2));

    // ---- CSR build (once; reused by both layers) + prescale ----
    hipMemsetAsync(deg, 0, (size_t)N * 4, stream);
    k_deg<<<(Ep + 255) / 256, 256, 0, stream>>>(pd, Ep, deg);
    k_scan1<<<nb, SCAN_B, 0, stream>>>(deg, N, part, bsum, dinv,
                                       (const float4*)x, (float4*)xs);
    k_scan2<<<1, 1024, 0, stream>>>(bsum, nb);
    k_scan3<<<(N + 256) / 256, 256, 0, stream>>>(part, bsum, N, Ep, rowptr, cursor);
    // 4 dst-range sweeps: temporal write clustering -> no write amplification
    {
        int grid = (Ep + 255) / 256;
        for (int s = 0; s < 4; ++s) {
            int lo = (int)((size_t)N * s / 4);
            int hi = (int)((size_t)N * (s + 1) / 4);
            k_fill_sweep<<<grid, 256, 0, stream>>>(ps, pd, Ep, lo, hi, cursor, csr);
        }
    }

    // ---- layer 1 ----
    k_gather<<<(N * 8 + 255) / 256, 256, 0, stream>>>(
        (const float4*)xs, dinv, rowptr, csr, N, (float4*)agg1);
    k_mlp1<<<(N + 7) / 8, 256, 0, stream>>>(agg1, dinv, W1, b1, W2, N, xl2s);

    // ---- layer 2 ----
    k_gather<<<(N * 8 + 255) / 256, 256, 0, stream>>>(
        (const float4*)xl2s, dinv, rowptr, csr, N, (float4*)agg2);
    k_mlp2<<<(N + 7) / 8, 256, 0, stream>>>(agg2, b2, Wm1, N, gt, gb);

    // ---- edge MLP over pos+neg edges (4 lanes/edge, fp16 tables) ----
    {
        size_t threads = (size_t)(Ep + En) * 4;
        k_edge<<<(int)((threads + 255) / 256), 256, 0, stream>>>(
            ps, pd, Ep, ns, nd, En,
            (const float4*)gt, (const float4*)gb,
            bm1, Wm2, bm2, (float2*)d_out);
    }
}

// Round 11
// 390.354 us; speedup vs baseline: 1.2494x; 1.1429x over previous
//
#include <hip/hip_runtime.h>
#include <hip/hip_fp16.h>

// GCN link classifier, fp32 compute, CSR-gather aggregation.
// R11: register-tiled MLP kernels (8 nodes x 4 outs per thread) — each weight
//      float4 feeds 32 FMAs, cutting L1 weight traffic 8x (was L1-BW-bound).
// Pipeline (14 dispatches):
//   memset deg; k_deg; k_scan1(+dinv+prescale); k_scan2; k_scan3; k_fill x4
//   k_gather(xs)->agg1; k_mlp1(agg1)->xl2s; k_gather(xl2s)->agg2;
//   k_mlp2(agg2)->gt,gb (fp16); k_edge (4 lanes/edge) -> out

#define HIDN 32
#define SCAN_B 256

struct __align__(8) Half4 { __half2 a, b; };

__global__ void k_deg(const int* __restrict__ dst, int E, int* __restrict__ deg) {
    int e = blockIdx.x * blockDim.x + threadIdx.x;
    if (e < E) atomicAdd(&deg[dst[e]], 1);
}

// per-block exclusive scan; bsum[b] = block total; dinv = rsqrt(deg+1);
// also prescale xs = dinv * x for this block's 256 nodes.
__global__ void k_scan1(const int* __restrict__ deg, int N,
                        int* __restrict__ part, int* __restrict__ bsum,
                        float* __restrict__ dinv,
                        const float4* __restrict__ x4, float4* __restrict__ xs4) {
    __shared__ int sh[SCAN_B];
    __shared__ float dsh[SCAN_B];
    int t = threadIdx.x, i = blockIdx.x * SCAN_B + t;
    int v = (i < N) ? deg[i] : 0;
    float dv = rsqrtf((float)(v + 1));       // +1 = self loop
    if (i < N) dinv[i] = dv;
    dsh[t] = dv;
    sh[t] = v; __syncthreads();
    for (int o = 1; o < SCAN_B; o <<= 1) {
        int a = (t >= o) ? sh[t - o] : 0;
        __syncthreads();
        sh[t] += a;
        __syncthreads();
    }
    if (i < N) part[i] = sh[t] - v;          // exclusive
    if (t == SCAN_B - 1) bsum[blockIdx.x] = sh[t];
#pragma unroll
    for (int it = 0; it < 8; ++it) {
        int q = it * SCAN_B + t;             // quad within block
        int g = blockIdx.x * (SCAN_B * 8) + q;
        if (g < N * 8) {
            float w = dsh[q >> 3];
            float4 a = x4[g];
            a.x *= w; a.y *= w; a.z *= w; a.w *= w;
            xs4[g] = a;
        }
    }
}

// single-block exclusive scan of block sums (nb <= 1024)
__global__ void k_scan2(int* __restrict__ bsum, int nb) {
    __shared__ int sh[1024];
    int t = threadIdx.x;
    int v = (t < nb) ? bsum[t] : 0;
    sh[t] = v; __syncthreads();
    for (int o = 1; o < 1024; o <<= 1) {
        int a = (t >= o) ? sh[t - o] : 0;
        __syncthreads();
        sh[t] += a;
        __syncthreads();
    }
    if (t < nb) bsum[t] = sh[t] - v;         // exclusive, in place
}

// rowptr[i] = part[i] + bsum[i/SCAN_B]; cursor = rowptr; rowptr[N] = E
__global__ void k_scan3(const int* __restrict__ part, const int* __restrict__ bsum,
                        int N, int E, int* __restrict__ rowptr, int* __restrict__ cursor) {
    int i = blockIdx.x * blockDim.x + threadIdx.x;
    if (i < N) {
        int r = part[i] + bsum[i / SCAN_B];
        rowptr[i] = r;
        cursor[i] = r;
    }
    if (i == N) rowptr[N] = E;
}

// sweep-partitioned fill: only edges with dst in [lo,hi) are placed.
__global__ void k_fill_sweep(const int* __restrict__ src, const int* __restrict__ dst,
                             int E, int lo, int hi,
                             int* __restrict__ cursor, int* __restrict__ csr) {
    int e = blockIdx.x * blockDim.x + threadIdx.x;
    if (e >= E) return;
    int d = dst[e];
    if (d >= lo && d < hi) {
        int j = atomicAdd(&cursor[d], 1);
        csr[j] = src[e];
    }
}

// agg[i] = dinv[i] * ( tbl[i] + Sum_{s in inlist(i)} tbl[s] )   (tbl pre-scaled)
// 8 threads/node (one float4 quad each); unroll-4 independent row loads.
__global__ void k_gather(const float4* __restrict__ tbl, const float* __restrict__ dinv,
                         const int* __restrict__ rowptr, const int* __restrict__ csr,
                         int N, float4* __restrict__ out) {
    int t = blockIdx.x * blockDim.x + threadIdx.x;   // N*8
    if (t >= N * 8) return;
    int i = t >> 3, c = t & 7;
    float di = dinv[i];
    float4 acc = tbl[(size_t)i * 8 + c];             // self-loop term
    int p = rowptr[i], end = rowptr[i + 1];
    for (; p + 3 < end; p += 4) {
        int s0 = csr[p], s1 = csr[p + 1], s2 = csr[p + 2], s3 = csr[p + 3];
        float4 a0 = tbl[(size_t)s0 * 8 + c];
        float4 a1 = tbl[(size_t)s1 * 8 + c];
        float4 a2 = tbl[(size_t)s2 * 8 + c];
        float4 a3 = tbl[(size_t)s3 * 8 + c];
        acc.x += (a0.x + a1.x) + (a2.x + a3.x);
        acc.y += (a0.y + a1.y) + (a2.y + a3.y);
        acc.z += (a0.z + a1.z) + (a2.z + a3.z);
        acc.w += (a0.w + a1.w) + (a2.w + a3.w);
    }
    for (; p < end; ++p) {
        float4 a = tbl[(size_t)csr[p] * 8 + c];
        acc.x += a.x; acc.y += a.y; acc.z += a.z; acc.w += a.w;
    }
    acc.x *= di; acc.y *= di; acc.z *= di; acc.w *= di;
    out[t] = acc;
}

// ---- k_mlp1: 64 nodes/block, register-tiled.
// Stage1: thread (r=t>>5, j=t&31) computes h1[8 nodes][4j..4j+3];
//         acts from aT[k][node] (broadcast scalar), W1 float4 from L1 (32 FMA each).
// Stage2: K split in 4 lane-slices (ko=j>>3); h1 from hT[node][k] float4;
//         shfl_xor(8,16) reduces slices; ko==0 writes xl2s = dinv*(h1@W2).
__global__ __launch_bounds__(256) void k_mlp1(
        const float4* __restrict__ agg1, const float* __restrict__ dinv,
        const float* __restrict__ W1, const float* __restrict__ b1,
        const float* __restrict__ W2, int N, float4* __restrict__ xl2s) {
    __shared__ float aT[32][65];     // acts transposed [feat][node]
    __shared__ float hT[64][129];    // h1 [node][feat+pad]
    int t = threadIdx.x;
    int base = blockIdx.x * 64;
#pragma unroll
    for (int it = 0; it < 2; ++it) {
        int idx = it * 256 + t;                 // 0..511 = 64 nodes x 8 quads
        int n = idx >> 3, q = idx & 7;
        int gi = base + n;
        float4 v = (gi < N) ? agg1[(size_t)gi * 8 + q] : make_float4(0.f, 0.f, 0.f, 0.f);
        aT[q * 4 + 0][n] = v.x; aT[q * 4 + 1][n] = v.y;
        aT[q * 4 + 2][n] = v.z; aT[q * 4 + 3][n] = v.w;
    }
    __syncthreads();
    int j = t & 31, r = t >> 5;
    int n0 = r * 8;
    float acc[8][4];
    {
        float4 bq = *reinterpret_cast<const float4*>(&b1[4 * j]);
#pragma unroll
        for (int n = 0; n < 8; ++n) {
            acc[n][0] = bq.x; acc[n][1] = bq.y; acc[n][2] = bq.z; acc[n][3] = bq.w;
        }
    }
#pragma unroll
    for (int k = 0; k < 32; ++k) {
        float4 w = *reinterpret_cast<const float4*>(&W1[k * 128 + 4 * j]);
#pragma unroll
        for (int n = 0; n < 8; ++n) {
            float a = aT[k][n0 + n];
            acc[n][0] = fmaf(a, w.x, acc[n][0]);
            acc[n][1] = fmaf(a, w.y, acc[n][1]);
            acc[n][2] = fmaf(a, w.z, acc[n][2]);
            acc[n][3] = fmaf(a, w.w, acc[n][3]);
        }
    }
#pragma unroll
    for (int n = 0; n < 8; ++n) {
        float4 h;
        h.x = fmaxf(acc[n][0], 0.f); h.y = fmaxf(acc[n][1], 0.f);
        h.z = fmaxf(acc[n][2], 0.f); h.w = fmaxf(acc[n][3], 0.f);
        *reinterpret_cast<float4*>(&hT[n0 + n][4 * j]) = h;
    }
    __syncthreads();
    int jo = j & 7, ko = j >> 3;
    float acc2[8][4];
#pragma unroll
    for (int n = 0; n < 8; ++n) { acc2[n][0] = acc2[n][1] = acc2[n][2] = acc2[n][3] = 0.f; }
#pragma unroll
    for (int kk = 0; kk < 8; ++kk) {
        int kbase = ko * 32 + 4 * kk;
        float4 h4[8];
#pragma unroll
        for (int n = 0; n < 8; ++n)
            h4[n] = *reinterpret_cast<const float4*>(&hT[n0 + n][kbase]);
#pragma unroll
        for (int c = 0; c < 4; ++c) {
            float4 w = *reinterpret_cast<const float4*>(&W2[(kbase + c) * 32 + 4 * jo]);
#pragma unroll
            for (int n = 0; n < 8; ++n) {
                float a = (c == 0) ? h4[n].x : (c == 1) ? h4[n].y : (c == 2) ? h4[n].z : h4[n].w;
                acc2[n][0] = fmaf(a, w.x, acc2[n][0]);
                acc2[n][1] = fmaf(a, w.y, acc2[n][1]);
                acc2[n][2] = fmaf(a, w.z, acc2[n][2]);
                acc2[n][3] = fmaf(a, w.w, acc2[n][3]);
            }
        }
    }
#pragma unroll
    for (int n = 0; n < 8; ++n)
#pragma unroll
        for (int c = 0; c < 4; ++c) {
            acc2[n][c] += __shfl_xor(acc2[n][c], 8);
            acc2[n][c] += __shfl_xor(acc2[n][c], 16);
        }
    if (ko == 0) {
#pragma unroll
        for (int n = 0; n < 8; ++n) {
            int gi = base + n0 + n;
            if (gi < N) {
                float d = dinv[gi];
                xl2s[(size_t)gi * 8 + jo] =
                    make_float4(acc2[n][0] * d, acc2[n][1] * d, acc2[n][2] * d, acc2[n][3] * d);
            }
        }
    }
}

// ---- k_mlp2: 128 nodes/block, register-tiled; h2 = relu(agg2+b2) staged in LDS.
// thread (r=t>>4 node octet, j=t&15): half=j>>3 picks gt/gb, jo=j&7 the out quad;
// 8 nodes x 4 outs per thread; W float4 feeds 32 FMA. fp16 packed output.
__global__ __launch_bounds__(256) void k_mlp2(
        const float4* __restrict__ agg2, const float* __restrict__ b2,
        const float* __restrict__ Wm1, int N,
        __half* __restrict__ gt, __half* __restrict__ gb) {
    __shared__ float hT[32][129];    // h2 transposed [feat][node]
    int t = threadIdx.x;
    int base = blockIdx.x * 128;
    const float4* b2q = reinterpret_cast<const float4*>(b2);
#pragma unroll
    for (int it = 0; it < 4; ++it) {
        int idx = it * 256 + t;                 // 0..1023 = 128 nodes x 8 quads
        int n = idx >> 3, q = idx & 7;
        int gi = base + n;
        float4 v = (gi < N) ? agg2[(size_t)gi * 8 + q] : make_float4(0.f, 0.f, 0.f, 0.f);
        float4 bb = b2q[q];
        hT[q * 4 + 0][n] = fmaxf(v.x + bb.x, 0.f);
        hT[q * 4 + 1][n] = fmaxf(v.y + bb.y, 0.f);
        hT[q * 4 + 2][n] = fmaxf(v.z + bb.z, 0.f);
        hT[q * 4 + 3][n] = fmaxf(v.w + bb.w, 0.f);
    }
    __syncthreads();
    int j = t & 15, r = t >> 4;      // r: node octet (0..15), j: out quad of [gt|gb]
    int n0 = r * 8;
    int half = j >> 3, jo = j & 7;
    float acc[8][4];
#pragma unroll
    for (int n = 0; n < 8; ++n) { acc[n][0] = acc[n][1] = acc[n][2] = acc[n][3] = 0.f; }
#pragma unroll
    for (int k = 0; k < 32; ++k) {
        float4 w = *reinterpret_cast<const float4*>(&Wm1[(k + half * 32) * 32 + 4 * jo]);
#pragma unroll
        for (int n = 0; n < 8; ++n) {
            float a = hT[k][n0 + n];
            acc[n][0] = fmaf(a, w.x, acc[n][0]);
            acc[n][1] = fmaf(a, w.y, acc[n][1]);
            acc[n][2] = fmaf(a, w.z, acc[n][2]);
            acc[n][3] = fmaf(a, w.w, acc[n][3]);
        }
    }
    __half* dsttab = half ? gb : gt;
#pragma unroll
    for (int n = 0; n < 8; ++n) {
        int gi = base + n0 + n;
        if (gi < N) {
            Half4 hv;
            hv.a = __floats2half2_rn(acc[n][0], acc[n][1]);
            hv.b = __floats2half2_rn(acc[n][2], acc[n][3]);
            *reinterpret_cast<Half4*>(&dsttab[(size_t)gi * 32 + 4 * jo]) = hv;
        }
    }
}

// out[e] = relu(gt[u] + gb[v] + bm1) @ Wm2 + bm2
// 4 lanes/edge: lane q loads 16B (8 halves) of gt[u] and gb[v], computes 8
// hidden units; 4-lane shuffle reduce; lane 0 writes float2.
__global__ void k_edge(const int* __restrict__ ps, const int* __restrict__ pd, int Ep,
                       const int* __restrict__ ns, const int* __restrict__ nd, int En,
                       const float4* __restrict__ gt4, const float4* __restrict__ gb4,
                       const float* __restrict__ bm1, const float* __restrict__ Wm2,
                       const float* __restrict__ bm2, float2* __restrict__ out) {
    int t = blockIdx.x * blockDim.x + threadIdx.x;   // E*4 threads
    int e = t >> 2, q = t & 3;
    int E = Ep + En;
    if (e >= E) return;
    int u, v;
    if (e < Ep) { u = ps[e]; v = pd[e]; }
    else        { u = ns[e - Ep]; v = nd[e - Ep]; }
    float4 araw = gt4[(size_t)u * 4 + q];            // 8 halves of gt row
    float4 braw = gb4[(size_t)v * 4 + q];            // 8 halves of gb row
    const __half* ah = (const __half*)&araw;
    const __half* bh = (const __half*)&braw;
    int k0 = q * 8;
    float o0 = 0.f, o1 = 0.f;
#pragma unroll
    for (int r = 0; r < 8; ++r) {
        float h = fmaxf(__half2float(ah[r]) + __half2float(bh[r]) + bm1[k0 + r], 0.f);
        o0 = fmaf(h, Wm2[(k0 + r) * 2 + 0], o0);
        o1 = fmaf(h, Wm2[(k0 + r) * 2 + 1], o1);
    }
    o0 += __shfl_down(o0, 2, 4); o1 += __shfl_down(o1, 2, 4);
    o0 += __shfl_down(o0, 1, 4); o1 += __shfl_down(o1, 1, 4);
    if (q == 0) out[e] = make_float2(o0 + bm2[0], o1 + bm2[1]);
}

extern "C" void kernel_launch(void* const* d_in, const int* in_sizes, int n_in,
                              void* d_out, int out_size, void* d_ws, size_t ws_size,
                              hipStream_t stream) {
    const float* x   = (const float*)d_in[0];
    const int*   pei = (const int*)d_in[1];
    const int*   nei = (const int*)d_in[2];
    const float* W1  = (const float*)d_in[3];
    const float* b1  = (const float*)d_in[4];
    const float* W2  = (const float*)d_in[5];
    const float* b2  = (const float*)d_in[6];
    const float* Wm1 = (const float*)d_in[7];
    const float* bm1 = (const float*)d_in[8];
    const float* Wm2 = (const float*)d_in[9];
    const float* bm2 = (const float*)d_in[10];

    const int N  = in_sizes[0] / HIDN;
    const int Ep = in_sizes[1] / 2;
    const int En = in_sizes[2] / 2;
    const int* ps = pei;            // pos src
    const int* pd = pei + Ep;       // pos dst
    const int* ns = nei;
    const int* nd = nei + En;
    const int nb = (N + SCAN_B - 1) / SCAN_B;   // scan blocks (<= 1024)

    // workspace layout (256B-aligned slabs)
    char* ws = (char*)d_ws;
    size_t off = 0;
    auto alloc = [&](size_t bytes) { size_t o = off; off += (bytes + 255) & ~(size_t)255; return o; };
    int*    deg    = (int*)(ws + alloc((size_t)N * 4));
    float*  dinv   = (float*)(ws + alloc((size_t)N * 4));
    int*    part   = (int*)(ws + alloc((size_t)N * 4));
    int*    bsum   = (int*)(ws + alloc((size_t)1024 * 4));
    int*    rowptr = (int*)(ws + alloc((size_t)(N + 1) * 4));
    int*    cursor = (int*)(ws + alloc((size_t)N * 4));
    int*    csr    = (int*)(ws + alloc((size_t)Ep * 4));
    float*  xs     = (float*)(ws + alloc((size_t)N * HIDN * 4));
    float*  agg1   = (float*)(ws + alloc((size_t)N * HIDN * 4));
    float*  xl2s   = (float*)(ws + alloc((size_t)N * HIDN * 4));
    float*  agg2   = (float*)(ws + alloc((size_t)N * HIDN * 4));
    __half* gt     = (__half*)(ws + alloc((size_t)N * HIDN * 2));
    __half* gb     = (__half*)(ws + alloc((size_t)N * HIDN * 2));

    // ---- CSR build (once; reused by both layers) + prescale ----
    hipMemsetAsync(deg, 0, (size_t)N * 4, stream);
    k_deg<<<(Ep + 255) / 256, 256, 0, stream>>>(pd, Ep, deg);
    k_scan1<<<nb, SCAN_B, 0, stream>>>(deg, N, part, bsum, dinv,
                                       (const float4*)x, (float4*)xs);
    k_scan2<<<1, 1024, 0, stream>>>(bsum, nb);
    k_scan3<<<(N + 256) / 256, 256, 0, stream>>>(part, bsum, N, Ep, rowptr, cursor);
    // 4 dst-range sweeps: temporal write clustering -> no write amplification
    {
        int grid = (Ep + 255) / 256;
        for (int s = 0; s < 4; ++s) {
            int lo = (int)((size_t)N * s / 4);
            int hi = (int)((size_t)N * (s + 1) / 4);
            k_fill_sweep<<<grid, 256, 0, stream>>>(ps, pd, Ep, lo, hi, cursor, csr);
        }
    }

    // ---- layer 1 ----
    k_gather<<<(N * 8 + 255) / 256, 256, 0, stream>>>(
        (const float4*)xs, dinv, rowptr, csr, N, (float4*)agg1);
    k_mlp1<<<(N + 63) / 64, 256, 0, stream>>>(
        (const float4*)agg1, dinv, W1, b1, W2, N, (float4*)xl2s);

    // ---- layer 2 ----
    k_gather<<<(N * 8 + 255) / 256, 256, 0, stream>>>(
        (const float4*)xl2s, dinv, rowptr, csr, N, (float4*)agg2);
    k_mlp2<<<(N + 127) / 128, 256, 0, stream>>>(
        (const float4*)agg2, b2, Wm1, N, gt, gb);

    // ---- edge MLP over pos+neg edges (4 lanes/edge, fp16 tables) ----
    {
        size_t threads = (size_t)(Ep + En) * 4;
        k_edge<<<(int)((threads + 255) / 256), 256, 0, stream>>>(
            ps, pd, Ep, ns, nd, En,
            (const float4*)gt, (const float4*)gb,
            bm1, Wm2, bm2, (float2*)d_out);
    }
}